// Round 12
// baseline (330.957 us; speedup 1.0000x reference)
//
#include <hip/hip_runtime.h>
#include <hip/hip_bf16.h>
#include <stdint.h>

typedef __attribute__((ext_vector_type(4))) float f32x4;
typedef __attribute__((ext_vector_type(8))) short bf16x8;

#define D 128
#define GLOBAL_AS __attribute__((address_space(1)))
#define LDS_AS __attribute__((address_space(3)))

__device__ inline short f2bf(float x) {
    __hip_bfloat16 h = __float2bfloat16(x);
    return __builtin_bit_cast(short, h);
}

__device__ inline bf16x8 pack8(f32x4 lo, f32x4 hi) {
    bf16x8 b;
    b[0] = f2bf(lo[0]); b[1] = f2bf(lo[1]); b[2] = f2bf(lo[2]); b[3] = f2bf(lo[3]);
    b[4] = f2bf(hi[0]); b[5] = f2bf(hi[1]); b[6] = f2bf(hi[2]); b[7] = f2bf(hi[3]);
    return b;
}

__device__ inline unsigned int pack2bf(float a, float b) {
    unsigned int ua = (unsigned int)(unsigned short)f2bf(a);
    unsigned int ub = (unsigned int)(unsigned short)f2bf(b);
    return ua | (ub << 16);
}

// ---- merged prep: bf16-ify X tables (for-tables + optionally self tables),
//      pack weights, row histogram ----

__global__ __launch_bounds__(256)
void prep_kernel(const float* __restrict__ Xa, const float* __restrict__ Xb,
                 unsigned short* __restrict__ x16a, unsigned short* __restrict__ x16b,
                 const float* __restrict__ Sa, const float* __restrict__ Sb,
                 unsigned short* __restrict__ xs16a, unsigned short* __restrict__ xs16b,
                 const float* __restrict__ Wg_self, const float* __restrict__ Wg_neigh,
                 const float* __restrict__ Ws_self, const float* __restrict__ Ws_neigh,
                 short* __restrict__ Wcat,
                 const int* __restrict__ rowA, int EA,
                 const int* __restrict__ rowB, int NGoff,
                 int* __restrict__ cnt,
                 int n8a, int n8b, int n8sa, int n8sb, int Etot)
{
    int t = blockIdx.x * 256 + threadIdx.x;
    if (t < n8a) {
        f32x4 lo = *reinterpret_cast<const f32x4*>(Xa + (size_t)t * 8);
        f32x4 hi = *reinterpret_cast<const f32x4*>(Xa + (size_t)t * 8 + 4);
        *reinterpret_cast<bf16x8*>(x16a + (size_t)t * 8) = pack8(lo, hi);
        return;
    }
    t -= n8a;
    if (t < n8b) {
        f32x4 lo = *reinterpret_cast<const f32x4*>(Xb + (size_t)t * 8);
        f32x4 hi = *reinterpret_cast<const f32x4*>(Xb + (size_t)t * 8 + 4);
        *reinterpret_cast<bf16x8*>(x16b + (size_t)t * 8) = pack8(lo, hi);
        return;
    }
    t -= n8b;
    if (t < n8sa) {
        f32x4 lo = *reinterpret_cast<const f32x4*>(Sa + (size_t)t * 8);
        f32x4 hi = *reinterpret_cast<const f32x4*>(Sa + (size_t)t * 8 + 4);
        *reinterpret_cast<bf16x8*>(xs16a + (size_t)t * 8) = pack8(lo, hi);
        return;
    }
    t -= n8sa;
    if (t < n8sb) {
        f32x4 lo = *reinterpret_cast<const f32x4*>(Sb + (size_t)t * 8);
        f32x4 hi = *reinterpret_cast<const f32x4*>(Sb + (size_t)t * 8 + 4);
        *reinterpret_cast<bf16x8*>(xs16b + (size_t)t * 8) = pack8(lo, hi);
        return;
    }
    t -= n8sb;
    if (t < 2 * 128 * 32) {
        int dir = t >> 12;
        int rem = t & 4095;
        int j = rem >> 5;
        int k = (rem & 31) * 8;
        const float* Wself  = dir ? Ws_self  : Wg_self;
        const float* Wneigh = dir ? Ws_neigh : Wg_neigh;
        const float* src = (k < 128) ? (Wself + j * D + k) : (Wneigh + j * D + (k - 128));
        f32x4 lo = *reinterpret_cast<const f32x4*>(src);
        f32x4 hi = *reinterpret_cast<const f32x4*>(src + 4);
        *reinterpret_cast<bf16x8*>(Wcat + (size_t)dir * 32768 + j * 256 + k) = pack8(lo, hi);
        return;
    }
    t -= 2 * 128 * 32;
    if (t < Etot) {
        int r = (t < EA) ? rowA[t] : (rowB[t - EA] + NGoff);
        atomicAdd(&cnt[r], 1);
    }
}

// ---------------- scans ----------------

__global__ __launch_bounds__(256)
void scan1_kernel(const int* __restrict__ cnt, int* __restrict__ part,
                  int* __restrict__ blksums, int N)
{
    __shared__ int wsum[4];
    int t = threadIdx.x;
    int base = blockIdx.x * 1024 + t * 4;
    int v0 = base + 0 < N ? cnt[base + 0] : 0;
    int v1 = base + 1 < N ? cnt[base + 1] : 0;
    int v2 = base + 2 < N ? cnt[base + 2] : 0;
    int v3 = base + 3 < N ? cnt[base + 3] : 0;
    int s = v0 + v1 + v2 + v3;
    int lane = t & 63, w = t >> 6;
    int x = s;
#pragma unroll
    for (int off = 1; off < 64; off <<= 1) {
        int y = __shfl_up(x, off);
        if (lane >= off) x += y;
    }
    if (lane == 63) wsum[w] = x;
    __syncthreads();
    int woff = 0;
    for (int i = 0; i < w; ++i) woff += wsum[i];
    int incl = x + woff;
    int excl = incl - s;
    if (base + 0 < N) part[base + 0] = excl;
    if (base + 1 < N) part[base + 1] = excl + v0;
    if (base + 2 < N) part[base + 2] = excl + v0 + v1;
    if (base + 3 < N) part[base + 3] = excl + v0 + v1 + v2;
    if (t == 255) blksums[blockIdx.x] = incl;
}

__global__ __launch_bounds__(256)
void scan2_kernel(int* __restrict__ blksums, int nb)
{
    __shared__ int wsum[4];
    int t = threadIdx.x;
    int v = t < nb ? blksums[t] : 0;
    int lane = t & 63, w = t >> 6;
    int x = v;
#pragma unroll
    for (int off = 1; off < 64; off <<= 1) {
        int y = __shfl_up(x, off);
        if (lane >= off) x += y;
    }
    if (lane == 63) wsum[w] = x;
    __syncthreads();
    int woff = 0;
    for (int i = 0; i < w; ++i) woff += wsum[i];
    int excl = x + woff - v;
    if (t < nb) blksums[t] = excl;
}

__global__ __launch_bounds__(256)
void scan3_kernel(int* __restrict__ cursor, const int* __restrict__ blksums, int N)
{
    int i = blockIdx.x * 256 + threadIdx.x;
    if (i < N) cursor[i] += blksums[i >> 10];
}

// ---- XCD-partitioned CSR fill (proven R11): 8 blocks per chunk; block grp only
// scatters edges with ((gid>>6)&7)==grp -> each XCD L2 dirties 1/8 of pairs.
#define FILL_CHUNK 2048
__global__ __launch_bounds__(256)
void fill2x_kernel(const int* __restrict__ rowA, const int* __restrict__ colA,
                   const float* __restrict__ valA, int EA,
                   const int* __restrict__ rowB, const int* __restrict__ colB,
                   const float* __restrict__ valB, int NGoff,
                   int* __restrict__ cursor, int2* __restrict__ pairs, int Etot)
{
    int chunk = blockIdx.x >> 3;
    int grp   = blockIdx.x & 7;
    int base  = chunk * FILL_CHUNK;
#pragma unroll 1
    for (int i = threadIdx.x; i < FILL_CHUNK; i += 256) {
        int e = base + i;
        if (e >= Etot) break;
        int gid = (e < EA) ? rowA[e] : (rowB[e - EA] + NGoff);
        if (((gid >> 6) & 7) != grp) continue;
        int c; float v;
        if (e < EA) { c = colA[e]; v = valA[e]; }
        else { int e2 = e - EA; c = colB[e2]; v = valB[e2]; }
        int p = atomicAdd(&cursor[gid], 1);
        pairs[p] = make_int2(c, __float_as_int(v));
    }
}

// ---------------- standalone gather: one WAVE per row, bf16 table -> bf16 neigh ----
__global__ __launch_bounds__(256)
void gather_kernel(const unsigned short* __restrict__ X16_0,
                   const unsigned short* __restrict__ X16_1,
                   const int* __restrict__ cnt, const int* __restrict__ endpos,
                   const int2* __restrict__ pairs,
                   unsigned short* __restrict__ neigh16, int NG, int N)
{
    int wid = (blockIdx.x * 256 + threadIdx.x) >> 6;
    if (wid >= N) return;
    int lane = threadIdx.x & 63;
    const unsigned short* X16 = (wid < NG) ? X16_0 : X16_1;
    int n = __builtin_amdgcn_readfirstlane(cnt[wid]);
    int s = __builtin_amdgcn_readfirstlane(endpos[wid]) - n;
    float acc0 = 0.f, acc1 = 0.f;
#pragma unroll 1
    for (int j = 0; j < n; j += 8) {
        int2 p[8]; unsigned int x[8];
#pragma unroll
        for (int u = 0; u < 8; ++u) {
            int idx = (j + u < n) ? j + u : n - 1;
            p[u] = pairs[s + idx];
        }
#pragma unroll
        for (int u = 0; u < 8; ++u)
            x[u] = *reinterpret_cast<const unsigned int*>(X16 + (size_t)p[u].x * D + lane * 2);
#pragma unroll
        for (int u = 0; u < 8; ++u) {
            float v = (j + u < n) ? __int_as_float(p[u].y) : 0.f;
            acc0 += __uint_as_float(x[u] << 16) * v;
            acc1 += __uint_as_float(x[u] & 0xffff0000u) * v;
        }
    }
    ((unsigned int*)neigh16)[(size_t)wid * 64 + lane] = pack2bf(acc0, acc1);
}

// ---------------- barrier-free, LDS-free GEMM + relu ----------------
// All A-operands (self + neigh) are bf16 row-major in global memory, so every
// MFMA fragment is one direct 16B/lane load (a quarter-wave covers a whole 64B
// line of one row). 32 rows/block, 4 waves x (2 row-tiles x 2 col-tiles).
// No __syncthreads, no LDS, no pack VALU; compiler handles counted vmcnt.
__global__ __launch_bounds__(256)
void gemm16b_kernel(const unsigned short* __restrict__ xs16_0,
                    const unsigned short* __restrict__ xs16_1,
                    const unsigned short* __restrict__ neigh16,
                    float* __restrict__ out0, int n0,
                    float* __restrict__ out1, int n1,
                    const short* __restrict__ Wcat)
{
    const int ROWS = 32;
    int blocks0 = (n0 + ROWS - 1) / ROWS;

    const unsigned short* xs16; float* out; int nRows, r0base, csr0; const short* Wb;
    if ((int)blockIdx.x < blocks0) {
        xs16 = xs16_0; out = out0; nRows = n0;
        r0base = blockIdx.x * ROWS; csr0 = 0; Wb = Wcat;
    } else {
        xs16 = xs16_1; out = out1; nRows = n1;
        r0base = ((int)blockIdx.x - blocks0) * ROWS; csr0 = n0; Wb = Wcat + 32768;
    }

    const int tid = threadIdx.x, wave = tid >> 6, lane = tid & 63;
    const int l15 = lane & 15, lhi = lane >> 4;

    // A fragments: 32 independent 16B loads (HBM/L3), issued first.
    bf16x8 afrag[2][8];
#pragma unroll
    for (int it = 0; it < 2; ++it) {
        int R = r0base + it * 16 + l15; if (R > nRows - 1) R = nRows - 1;
#pragma unroll
        for (int kb = 0; kb < 4; ++kb)
            afrag[it][kb] = *reinterpret_cast<const bf16x8*>(
                xs16 + (size_t)R * D + kb * 32 + lhi * 8);
#pragma unroll
        for (int kb = 4; kb < 8; ++kb)
            afrag[it][kb] = *reinterpret_cast<const bf16x8*>(
                neigh16 + (size_t)(csr0 + R) * D + (kb - 4) * 32 + lhi * 8);
    }

    // Weight fragments (L2-resident).
    bf16x8 bfrag[2][8];
#pragma unroll
    for (int nn = 0; nn < 2; ++nn) {
        int j = wave * 32 + nn * 16 + l15;
#pragma unroll
        for (int kb = 0; kb < 8; ++kb)
            bfrag[nn][kb] = *reinterpret_cast<const bf16x8*>(
                Wb + (size_t)j * 256 + kb * 32 + lhi * 8);
    }

    // MFMA + relu + store. C/D layout: col = lane&15, row = (lane>>4)*4 + reg.
#pragma unroll
    for (int it = 0; it < 2; ++it) {
        f32x4 acc0 = {0.f, 0.f, 0.f, 0.f};
        f32x4 acc1 = {0.f, 0.f, 0.f, 0.f};
#pragma unroll
        for (int kb = 0; kb < 8; ++kb) {
            acc0 = __builtin_amdgcn_mfma_f32_16x16x32_bf16(afrag[it][kb], bfrag[0][kb], acc0, 0, 0, 0);
            acc1 = __builtin_amdgcn_mfma_f32_16x16x32_bf16(afrag[it][kb], bfrag[1][kb], acc1, 0, 0, 0);
        }
#pragma unroll
        for (int i2 = 0; i2 < 4; ++i2) {
            int rr = r0base + it * 16 + lhi * 4 + i2;
            if (rr < nRows) {
                float v0 = acc0[i2] > 0.f ? acc0[i2] : 0.f;
                float v1 = acc1[i2] > 0.f ? acc1[i2] : 0.f;
                out[(size_t)rr * D + wave * 32 + l15]      = v0;
                out[(size_t)rr * D + wave * 32 + 16 + l15] = v1;
            }
        }
    }
}

// ---------------- mid-fallback GEMM (R11 LDS version, if ws lacks xs16) ----------
__global__ __launch_bounds__(256)
void gemm16_kernel(const float* __restrict__ Xself0, const float* __restrict__ Xself1,
                   const unsigned short* __restrict__ neigh16,
                   float* __restrict__ out0, int n0,
                   float* __restrict__ out1, int n1,
                   const short* __restrict__ Wcat)
{
    __shared__ float A[32 * 128];
    const int ROWS = 32;
    int blocks0 = (n0 + ROWS - 1) / ROWS;

    const float* Xself; float* out; int nRows, r0base, csr0; const short* Wb;
    if ((int)blockIdx.x < blocks0) {
        Xself = Xself0; out = out0; nRows = n0;
        r0base = blockIdx.x * ROWS; csr0 = 0; Wb = Wcat;
    } else {
        Xself = Xself1; out = out1; nRows = n1;
        r0base = ((int)blockIdx.x - blocks0) * ROWS; csr0 = n0; Wb = Wcat + 32768;
    }

    const int tid = threadIdx.x, wave = tid >> 6, lane = tid & 63;
    const int l15 = lane & 15, lhi = lane >> 4;

#pragma unroll
    for (int i = 0; i < 8; i += 2) {
        int r = wave * 8 + i + (lane >> 5);
        int R = r0base + r; if (R > nRows - 1) R = nRows - 1;
        const float* g = Xself + (size_t)R * D + (((lane & 31) ^ (r & 7)) << 2);
        __builtin_amdgcn_global_load_lds((const GLOBAL_AS uint32_t*)g,
                                         (LDS_AS uint32_t*)(&A[(wave * 8 + i) * 128]),
                                         16, 0, 0);
    }

    bf16x8 bfrag[2][8];
#pragma unroll
    for (int nn = 0; nn < 2; ++nn) {
        int j = wave * 32 + nn * 16 + l15;
#pragma unroll
        for (int kb = 0; kb < 8; ++kb)
            bfrag[nn][kb] = *reinterpret_cast<const bf16x8*>(
                Wb + (size_t)j * 256 + kb * 32 + lhi * 8);
    }

    bf16x8 nfrag[2][4];
#pragma unroll
    for (int it = 0; it < 2; ++it) {
        int R = r0base + it * 16 + l15; if (R > nRows - 1) R = nRows - 1;
#pragma unroll
        for (int k4 = 0; k4 < 4; ++k4)
            nfrag[it][k4] = *reinterpret_cast<const bf16x8*>(
                neigh16 + (size_t)(csr0 + R) * D + k4 * 32 + lhi * 8);
    }

    asm volatile("s_waitcnt vmcnt(0)" ::: "memory");
    __syncthreads();

#pragma unroll
    for (int it = 0; it < 2; ++it) {
        int r = it * 16 + l15;
        int rx = r & 7;
        f32x4 acc0 = {0.f, 0.f, 0.f, 0.f};
        f32x4 acc1 = {0.f, 0.f, 0.f, 0.f};
#pragma unroll
        for (int kb = 0; kb < 8; ++kb) {
            bf16x8 af;
            if (kb < 4) {
                int c0 = kb * 8 + lhi * 2;
                f32x4 lo = *reinterpret_cast<const f32x4*>(&A[r * 128 + ((c0 ^ rx) << 2)]);
                f32x4 hi = *reinterpret_cast<const f32x4*>(&A[r * 128 + (((c0 + 1) ^ rx) << 2)]);
                af = pack8(lo, hi);
            } else {
                af = nfrag[it][kb - 4];
            }
            acc0 = __builtin_amdgcn_mfma_f32_16x16x32_bf16(af, bfrag[0][kb], acc0, 0, 0, 0);
            acc1 = __builtin_amdgcn_mfma_f32_16x16x32_bf16(af, bfrag[1][kb], acc1, 0, 0, 0);
        }
#pragma unroll
        for (int i2 = 0; i2 < 4; ++i2) {
            int rr = r0base + it * 16 + lhi * 4 + i2;
            if (rr < nRows) {
                float v0 = acc0[i2] > 0.f ? acc0[i2] : 0.f;
                float v1 = acc1[i2] > 0.f ? acc1[i2] : 0.f;
                out[(size_t)rr * D + wave * 32 + l15]      = v0;
                out[(size_t)rr * D + wave * 32 + 16 + l15] = v1;
            }
        }
    }
}

// ---------------- deep fallback: atomic scatter + register GEMM ------

__global__ __launch_bounds__(256)
void scatter_edges(const float* __restrict__ X, const int* __restrict__ row,
                   const int* __restrict__ col, const float* __restrict__ val,
                   float* out, int nE)
{
    int t = blockIdx.x * 256 + threadIdx.x;
    int e = t >> 5;
    if (e >= nE) return;
    int l = t & 31;
    int r = row[e];
    int c = col[e];
    float v = val[e];
    f32x4 x = *reinterpret_cast<const f32x4*>(X + (size_t)c * D + l * 4);
    float* o = out + (size_t)r * D + l * 4;
    unsafeAtomicAdd(o + 0, x[0] * v);
    unsafeAtomicAdd(o + 1, x[1] * v);
    unsafeAtomicAdd(o + 2, x[2] * v);
    unsafeAtomicAdd(o + 3, x[3] * v);
}

__global__ __launch_bounds__(256)
void gemm_relu_fb(const float* __restrict__ Xself, const float* __restrict__ Neigh,
                  const float* __restrict__ Wself, const float* __restrict__ Wneigh,
                  float* __restrict__ out, int nRows)
{
    const int tid  = threadIdx.x;
    const int wave = tid >> 6;
    const int lane = tid & 63;
    const int l15  = lane & 15;
    const int lhi  = lane >> 4;

    bf16x8 bfrag[2][8];
#pragma unroll
    for (int n = 0; n < 2; ++n) {
        int j = wave * 32 + n * 16 + l15;
#pragma unroll
        for (int kb = 0; kb < 8; ++kb) {
            int k = kb * 32 + lhi * 8;
            const float* src = (kb < 4) ? (Wself + j * D + k)
                                        : (Wneigh + j * D + (k - 128));
            f32x4 lo = *reinterpret_cast<const f32x4*>(src);
            f32x4 hi = *reinterpret_cast<const f32x4*>(src + 4);
            bfrag[n][kb] = pack8(lo, hi);
        }
    }

    int r0base = blockIdx.x * 128;
#pragma unroll 1
    for (int it = 0; it < 8; ++it) {
        int r0 = r0base + it * 16;
        if (r0 >= nRows) break;
        const float* xrow = Xself + (size_t)(r0 + l15) * D;
        const float* nrow = Neigh + (size_t)(r0 + l15) * D;
        bf16x8 afrag[8];
#pragma unroll
        for (int kb = 0; kb < 8; ++kb) {
            const float* src = (kb < 4) ? (xrow + kb * 32 + lhi * 8)
                                        : (nrow + (kb - 4) * 32 + lhi * 8);
            f32x4 lo = *reinterpret_cast<const f32x4*>(src);
            f32x4 hi = *reinterpret_cast<const f32x4*>(src + 4);
            afrag[kb] = pack8(lo, hi);
        }
        asm volatile("s_waitcnt vmcnt(0)" ::: "memory");
        __syncthreads();

        f32x4 acc0 = {0.f, 0.f, 0.f, 0.f};
        f32x4 acc1 = {0.f, 0.f, 0.f, 0.f};
#pragma unroll
        for (int kb = 0; kb < 8; ++kb) {
            acc0 = __builtin_amdgcn_mfma_f32_16x16x32_bf16(afrag[kb], bfrag[0][kb], acc0, 0, 0, 0);
            acc1 = __builtin_amdgcn_mfma_f32_16x16x32_bf16(afrag[kb], bfrag[1][kb], acc1, 0, 0, 0);
        }
#pragma unroll
        for (int i = 0; i < 4; ++i) {
            int rr = r0 + lhi * 4 + i;
            if (rr < nRows) {
                float v0 = acc0[i] > 0.f ? acc0[i] : 0.f;
                float v1 = acc1[i] > 0.f ? acc1[i] : 0.f;
                out[(size_t)rr * D + wave * 32 + l15]      = v0;
                out[(size_t)rr * D + wave * 32 + 16 + l15] = v1;
            }
        }
    }
}

// ---------------- launch ----------------

extern "C" void kernel_launch(void* const* d_in, const int* in_sizes, int n_in,
                              void* d_out, int out_size, void* d_ws, size_t ws_size,
                              hipStream_t stream)
{
    const float* Xg_self  = (const float*)d_in[0];
    const float* Xs_self  = (const float*)d_in[1];
    const float* Xs_for_g = (const float*)d_in[2];
    const float* Xg_for_s = (const float*)d_in[3];
    const int*   row_gs   = (const int*)d_in[4];
    const int*   col_gs   = (const int*)d_in[5];
    const float* val_gs   = (const float*)d_in[6];
    const int*   row_sg   = (const int*)d_in[7];
    const int*   col_sg   = (const int*)d_in[8];
    const float* val_sg   = (const float*)d_in[9];
    const float* Wg_self  = (const float*)d_in[10];
    const float* Wg_neigh = (const float*)d_in[11];
    const float* Ws_self  = (const float*)d_in[12];
    const float* Ws_neigh = (const float*)d_in[13];

    const int NG = in_sizes[0] / D;
    const int NS = in_sizes[1] / D;
    const int E1 = in_sizes[4];
    const int E2 = in_sizes[7];
    const int N  = NG + NS;
    const int Etot = E1 + E2;

    float* out_g = (float*)d_out;
    float* out_s = out_g + (size_t)NG * D;

    // ---- workspace layout ----
    size_t off = 0;
    auto alloc = [&](size_t bytes) -> size_t {
        off = (off + 255) & ~(size_t)255;
        size_t o = off;
        off += bytes;
        return o;
    };
    size_t x16g_o   = alloc(sizeof(short) * (size_t)NG * D);
    size_t x16s_o   = alloc(sizeof(short) * (size_t)NS * D);
    size_t wcat_o   = alloc(sizeof(short) * 2 * 128 * 256);
    size_t cnt_o    = alloc(sizeof(int) * N);
    size_t cursor_o = alloc(sizeof(int) * N);
    size_t pairs_o  = alloc(sizeof(int2) * (size_t)Etot);
    size_t blk_o    = alloc(sizeof(int) * 1024);
    size_t neigh_o  = alloc(sizeof(short) * (size_t)N * D);
    size_t base_bytes = off;
    size_t xs16g_o  = alloc(sizeof(short) * (size_t)NG * D);
    size_t xs16s_o  = alloc(sizeof(short) * (size_t)NS * D);
    size_t full_bytes = off;

    char* ws = (char*)d_ws;
    bool have_base = ws_size >= base_bytes;
    bool have_full = ws_size >= full_bytes;

    if (!have_base) {
        // ---- deep fallback: atomic scatter + in-place register GEMM ----
        hipMemsetAsync(d_out, 0, (size_t)out_size * sizeof(float), stream);
        {
            long long threads = (long long)E1 * 32;
            scatter_edges<<<(int)((threads + 255) / 256), 256, 0, stream>>>(
                Xs_for_g, row_gs, col_gs, val_gs, out_g, E1);
        }
        {
            long long threads = (long long)E2 * 32;
            scatter_edges<<<(int)((threads + 255) / 256), 256, 0, stream>>>(
                Xg_for_s, row_sg, col_sg, val_sg, out_s, E2);
        }
        gemm_relu_fb<<<(NG + 127) / 128, 256, 0, stream>>>(Xg_self, out_g, Wg_self, Wg_neigh, out_g, NG);
        gemm_relu_fb<<<(NS + 127) / 128, 256, 0, stream>>>(Xs_self, out_s, Ws_self, Ws_neigh, out_s, NS);
        return;
    }

    unsigned short* x16g    = (unsigned short*)(ws + x16g_o);
    unsigned short* x16s    = (unsigned short*)(ws + x16s_o);
    short* wcat             = (short*)(ws + wcat_o);
    int* cnt                = (int*)(ws + cnt_o);
    int* cursor             = (int*)(ws + cursor_o);
    int2* pairs             = (int2*)(ws + pairs_o);
    int* blk                = (int*)(ws + blk_o);
    unsigned short* neigh16 = (unsigned short*)(ws + neigh_o);
    unsigned short* xs16g   = have_full ? (unsigned short*)(ws + xs16g_o) : nullptr;
    unsigned short* xs16s   = have_full ? (unsigned short*)(ws + xs16s_o) : nullptr;

    const int n8a = NG * D / 8, n8b = NS * D / 8;
    const int n8sa = have_full ? n8a : 0;
    const int n8sb = have_full ? n8b : 0;

    hipMemsetAsync(cnt, 0, sizeof(int) * N, stream);

    {
        long long tot = (long long)n8a + n8b + n8sa + n8sb + 2 * 128 * 32 + Etot;
        prep_kernel<<<(int)((tot + 255) / 256), 256, 0, stream>>>(
            Xs_for_g, Xg_for_s, x16g, x16s,
            Xg_self, Xs_self, xs16g, xs16s,
            Wg_self, Wg_neigh, Ws_self, Ws_neigh, wcat,
            row_gs, E1, row_sg, NG, cnt, n8a, n8b, n8sa, n8sb, Etot);
    }

    int nb = (N + 1023) / 1024;   // 196 <= 256
    scan1_kernel<<<nb, 256, 0, stream>>>(cnt, cursor, blk, N);
    scan2_kernel<<<1, 256, 0, stream>>>(blk, nb);
    scan3_kernel<<<(N + 255) / 256, 256, 0, stream>>>(cursor, blk, N);

    {
        int nchunks = (Etot + FILL_CHUNK - 1) / FILL_CHUNK;
        fill2x_kernel<<<nchunks * 8, 256, 0, stream>>>(
            row_gs, col_gs, val_gs, E1, row_sg, col_sg, val_sg, NG, cursor, pairs, Etot);
    }

    gather_kernel<<<(int)(((long long)N * 64 + 255) / 256), 256, 0, stream>>>(
        x16g, x16s, cnt, cursor, pairs, neigh16, NG, N);

    int blocks0 = (NG + 31) / 32, blocks1 = (NS + 31) / 32;
    if (have_full) {
        gemm16b_kernel<<<blocks0 + blocks1, 256, 0, stream>>>(
            xs16g, xs16s, neigh16, out_g, NG, out_s, NS, wcat);
    } else {
        gemm16_kernel<<<blocks0 + blocks1, 256, 0, stream>>>(
            Xg_self, Xs_self, neigh16, out_g, NG, out_s, NS, wcat);
    }
}

// Round 13
// 330.165 us; speedup vs baseline: 1.0024x; 1.0024x over previous
//
#include <hip/hip_runtime.h>
#include <hip/hip_bf16.h>
#include <stdint.h>

typedef __attribute__((ext_vector_type(4))) float f32x4;
typedef __attribute__((ext_vector_type(8))) short bf16x8;

#define D 128
#define GLOBAL_AS __attribute__((address_space(1)))
#define LDS_AS __attribute__((address_space(3)))

__device__ inline short f2bf(float x) {
    __hip_bfloat16 h = __float2bfloat16(x);
    return __builtin_bit_cast(short, h);
}

__device__ inline bf16x8 pack8(f32x4 lo, f32x4 hi) {
    bf16x8 b;
    b[0] = f2bf(lo[0]); b[1] = f2bf(lo[1]); b[2] = f2bf(lo[2]); b[3] = f2bf(lo[3]);
    b[4] = f2bf(hi[0]); b[5] = f2bf(hi[1]); b[6] = f2bf(hi[2]); b[7] = f2bf(hi[3]);
    return b;
}

__device__ inline unsigned int pack2bf(float a, float b) {
    unsigned int ua = (unsigned int)(unsigned short)f2bf(a);
    unsigned int ub = (unsigned int)(unsigned short)f2bf(b);
    return ua | (ub << 16);
}

// ---- merged prep (R11 shape): bf16-ify the two gathered X tables + pack weights +
//      row histogram ----

__global__ __launch_bounds__(256)
void prep_kernel(const float* __restrict__ Xa, const float* __restrict__ Xb,
                 unsigned short* __restrict__ x16a, unsigned short* __restrict__ x16b,
                 const float* __restrict__ Wg_self, const float* __restrict__ Wg_neigh,
                 const float* __restrict__ Ws_self, const float* __restrict__ Ws_neigh,
                 short* __restrict__ Wcat,
                 const int* __restrict__ rowA, int EA,
                 const int* __restrict__ rowB, int NGoff,
                 int* __restrict__ cnt,
                 int n8a, int n8b, int Etot)
{
    int t = blockIdx.x * 256 + threadIdx.x;
    if (t < n8a) {
        f32x4 lo = *reinterpret_cast<const f32x4*>(Xa + (size_t)t * 8);
        f32x4 hi = *reinterpret_cast<const f32x4*>(Xa + (size_t)t * 8 + 4);
        *reinterpret_cast<bf16x8*>(x16a + (size_t)t * 8) = pack8(lo, hi);
        return;
    }
    t -= n8a;
    if (t < n8b) {
        f32x4 lo = *reinterpret_cast<const f32x4*>(Xb + (size_t)t * 8);
        f32x4 hi = *reinterpret_cast<const f32x4*>(Xb + (size_t)t * 8 + 4);
        *reinterpret_cast<bf16x8*>(x16b + (size_t)t * 8) = pack8(lo, hi);
        return;
    }
    t -= n8b;
    if (t < 2 * 128 * 32) {
        int dir = t >> 12;
        int rem = t & 4095;
        int j = rem >> 5;
        int k = (rem & 31) * 8;
        const float* Wself  = dir ? Ws_self  : Wg_self;
        const float* Wneigh = dir ? Ws_neigh : Wg_neigh;
        const float* src = (k < 128) ? (Wself + j * D + k) : (Wneigh + j * D + (k - 128));
        f32x4 lo = *reinterpret_cast<const f32x4*>(src);
        f32x4 hi = *reinterpret_cast<const f32x4*>(src + 4);
        *reinterpret_cast<bf16x8*>(Wcat + (size_t)dir * 32768 + j * 256 + k) = pack8(lo, hi);
        return;
    }
    t -= 2 * 128 * 32;
    if (t < Etot) {
        int r = (t < EA) ? rowA[t] : (rowB[t - EA] + NGoff);
        atomicAdd(&cnt[r], 1);
    }
}

// ---------------- scans ----------------

__global__ __launch_bounds__(256)
void scan1_kernel(const int* __restrict__ cnt, int* __restrict__ part,
                  int* __restrict__ blksums, int N)
{
    __shared__ int wsum[4];
    int t = threadIdx.x;
    int base = blockIdx.x * 1024 + t * 4;
    int v0 = base + 0 < N ? cnt[base + 0] : 0;
    int v1 = base + 1 < N ? cnt[base + 1] : 0;
    int v2 = base + 2 < N ? cnt[base + 2] : 0;
    int v3 = base + 3 < N ? cnt[base + 3] : 0;
    int s = v0 + v1 + v2 + v3;
    int lane = t & 63, w = t >> 6;
    int x = s;
#pragma unroll
    for (int off = 1; off < 64; off <<= 1) {
        int y = __shfl_up(x, off);
        if (lane >= off) x += y;
    }
    if (lane == 63) wsum[w] = x;
    __syncthreads();
    int woff = 0;
    for (int i = 0; i < w; ++i) woff += wsum[i];
    int incl = x + woff;
    int excl = incl - s;
    if (base + 0 < N) part[base + 0] = excl;
    if (base + 1 < N) part[base + 1] = excl + v0;
    if (base + 2 < N) part[base + 2] = excl + v0 + v1;
    if (base + 3 < N) part[base + 3] = excl + v0 + v1 + v2;
    if (t == 255) blksums[blockIdx.x] = incl;
}

__global__ __launch_bounds__(256)
void scan2_kernel(int* __restrict__ blksums, int nb)
{
    __shared__ int wsum[4];
    int t = threadIdx.x;
    int v = t < nb ? blksums[t] : 0;
    int lane = t & 63, w = t >> 6;
    int x = v;
#pragma unroll
    for (int off = 1; off < 64; off <<= 1) {
        int y = __shfl_up(x, off);
        if (lane >= off) x += y;
    }
    if (lane == 63) wsum[w] = x;
    __syncthreads();
    int woff = 0;
    for (int i = 0; i < w; ++i) woff += wsum[i];
    int excl = x + woff - v;
    if (t < nb) blksums[t] = excl;
}

__global__ __launch_bounds__(256)
void scan3_kernel(int* __restrict__ cursor, const int* __restrict__ blksums, int N)
{
    int i = blockIdx.x * 256 + threadIdx.x;
    if (i < N) cursor[i] += blksums[i >> 10];
}

// ---- XCD-partitioned CSR fill (proven R11): 8 blocks per chunk; block grp only
// scatters edges with ((gid>>6)&7)==grp -> each XCD L2 dirties 1/8 of pairs.
#define FILL_CHUNK 2048
__global__ __launch_bounds__(256)
void fill2x_kernel(const int* __restrict__ rowA, const int* __restrict__ colA,
                   const float* __restrict__ valA, int EA,
                   const int* __restrict__ rowB, const int* __restrict__ colB,
                   const float* __restrict__ valB, int NGoff,
                   int* __restrict__ cursor, int2* __restrict__ pairs, int Etot)
{
    int chunk = blockIdx.x >> 3;
    int grp   = blockIdx.x & 7;
    int base  = chunk * FILL_CHUNK;
#pragma unroll 1
    for (int i = threadIdx.x; i < FILL_CHUNK; i += 256) {
        int e = base + i;
        if (e >= Etot) break;
        int gid = (e < EA) ? rowA[e] : (rowB[e - EA] + NGoff);
        if (((gid >> 6) & 7) != grp) continue;
        int c; float v;
        if (e < EA) { c = colA[e]; v = valA[e]; }
        else { int e2 = e - EA; c = colB[e2]; v = valB[e2]; }
        int p = atomicAdd(&cursor[gid], 1);
        pairs[p] = make_int2(c, __float_as_int(v));
    }
}

// ---------------- standalone gather: one WAVE per row, bf16 table -> bf16 neigh ----
__global__ __launch_bounds__(256)
void gather_kernel(const unsigned short* __restrict__ X16_0,
                   const unsigned short* __restrict__ X16_1,
                   const int* __restrict__ cnt, const int* __restrict__ endpos,
                   const int2* __restrict__ pairs,
                   unsigned short* __restrict__ neigh16, int NG, int N)
{
    int wid = (blockIdx.x * 256 + threadIdx.x) >> 6;
    if (wid >= N) return;
    int lane = threadIdx.x & 63;
    const unsigned short* X16 = (wid < NG) ? X16_0 : X16_1;
    int n = __builtin_amdgcn_readfirstlane(cnt[wid]);
    int s = __builtin_amdgcn_readfirstlane(endpos[wid]) - n;
    float acc0 = 0.f, acc1 = 0.f;
#pragma unroll 1
    for (int j = 0; j < n; j += 8) {
        int2 p[8]; unsigned int x[8];
#pragma unroll
        for (int u = 0; u < 8; ++u) {
            int idx = (j + u < n) ? j + u : n - 1;
            p[u] = pairs[s + idx];
        }
#pragma unroll
        for (int u = 0; u < 8; ++u)
            x[u] = *reinterpret_cast<const unsigned int*>(X16 + (size_t)p[u].x * D + lane * 2);
#pragma unroll
        for (int u = 0; u < 8; ++u) {
            float v = (j + u < n) ? __int_as_float(p[u].y) : 0.f;
            acc0 += __uint_as_float(x[u] << 16) * v;
            acc1 += __uint_as_float(x[u] & 0xffff0000u) * v;
        }
    }
    ((unsigned int*)neigh16)[(size_t)wid * 64 + lane] = pack2bf(acc0, acc1);
}

// ---------------- barrier-free, LDS-free GEMM + relu (in-register self pack) ------
// Self operand read as f32 (two f32x4 per fragment) and packed to bf16 in registers;
// neigh operand read directly as bf16; weights from pre-packed Wcat (L2-resident).
// All 40 loads independent and issued up-front; no __syncthreads, no LDS, no
// vmcnt(0) drain -- compiler inserts counted waits per first use.
__global__ __launch_bounds__(256)
void gemm16c_kernel(const float* __restrict__ Xself0, const float* __restrict__ Xself1,
                    const unsigned short* __restrict__ neigh16,
                    float* __restrict__ out0, int n0,
                    float* __restrict__ out1, int n1,
                    const short* __restrict__ Wcat)
{
    const int ROWS = 32;
    int blocks0 = (n0 + ROWS - 1) / ROWS;

    const float* Xself; float* out; int nRows, r0base, csr0; const short* Wb;
    if ((int)blockIdx.x < blocks0) {
        Xself = Xself0; out = out0; nRows = n0;
        r0base = blockIdx.x * ROWS; csr0 = 0; Wb = Wcat;
    } else {
        Xself = Xself1; out = out1; nRows = n1;
        r0base = ((int)blockIdx.x - blocks0) * ROWS; csr0 = n0; Wb = Wcat + 32768;
    }

    const int tid = threadIdx.x, wave = tid >> 6, lane = tid & 63;
    const int l15 = lane & 15, lhi = lane >> 4;

    // Self rows as f32 (16 loads) -- longest latency, issue first.
    f32x4 slo[2][4], shi[2][4];
#pragma unroll
    for (int it = 0; it < 2; ++it) {
        int R = r0base + it * 16 + l15; if (R > nRows - 1) R = nRows - 1;
        const float* row = Xself + (size_t)R * D;
#pragma unroll
        for (int kb = 0; kb < 4; ++kb) {
            slo[it][kb] = *reinterpret_cast<const f32x4*>(row + kb * 32 + lhi * 8);
            shi[it][kb] = *reinterpret_cast<const f32x4*>(row + kb * 32 + lhi * 8 + 4);
        }
    }

    // Neigh fragments, direct bf16 (8 loads).
    bf16x8 nfrag[2][4];
#pragma unroll
    for (int it = 0; it < 2; ++it) {
        int R = r0base + it * 16 + l15; if (R > nRows - 1) R = nRows - 1;
#pragma unroll
        for (int k4 = 0; k4 < 4; ++k4)
            nfrag[it][k4] = *reinterpret_cast<const bf16x8*>(
                neigh16 + (size_t)(csr0 + R) * D + k4 * 32 + lhi * 8);
    }

    // Weight fragments (16 loads, L2-resident).
    bf16x8 bfrag[2][8];
#pragma unroll
    for (int nn = 0; nn < 2; ++nn) {
        int j = wave * 32 + nn * 16 + l15;
#pragma unroll
        for (int kb = 0; kb < 8; ++kb)
            bfrag[nn][kb] = *reinterpret_cast<const bf16x8*>(
                Wb + (size_t)j * 256 + kb * 32 + lhi * 8);
    }

    // MFMA + relu + store. C/D layout: col = lane&15, row = (lane>>4)*4 + reg.
#pragma unroll
    for (int it = 0; it < 2; ++it) {
        f32x4 acc0 = {0.f, 0.f, 0.f, 0.f};
        f32x4 acc1 = {0.f, 0.f, 0.f, 0.f};
#pragma unroll
        for (int kb = 0; kb < 8; ++kb) {
            bf16x8 af = (kb < 4) ? pack8(slo[it][kb], shi[it][kb]) : nfrag[it][kb - 4];
            acc0 = __builtin_amdgcn_mfma_f32_16x16x32_bf16(af, bfrag[0][kb], acc0, 0, 0, 0);
            acc1 = __builtin_amdgcn_mfma_f32_16x16x32_bf16(af, bfrag[1][kb], acc1, 0, 0, 0);
        }
#pragma unroll
        for (int i2 = 0; i2 < 4; ++i2) {
            int rr = r0base + it * 16 + lhi * 4 + i2;
            if (rr < nRows) {
                float v0 = acc0[i2] > 0.f ? acc0[i2] : 0.f;
                float v1 = acc1[i2] > 0.f ? acc1[i2] : 0.f;
                out[(size_t)rr * D + wave * 32 + l15]      = v0;
                out[(size_t)rr * D + wave * 32 + 16 + l15] = v1;
            }
        }
    }
}

// ---------------- deep fallback: atomic scatter + register GEMM ------

__global__ __launch_bounds__(256)
void scatter_edges(const float* __restrict__ X, const int* __restrict__ row,
                   const int* __restrict__ col, const float* __restrict__ val,
                   float* out, int nE)
{
    int t = blockIdx.x * 256 + threadIdx.x;
    int e = t >> 5;
    if (e >= nE) return;
    int l = t & 31;
    int r = row[e];
    int c = col[e];
    float v = val[e];
    f32x4 x = *reinterpret_cast<const f32x4*>(X + (size_t)c * D + l * 4);
    float* o = out + (size_t)r * D + l * 4;
    unsafeAtomicAdd(o + 0, x[0] * v);
    unsafeAtomicAdd(o + 1, x[1] * v);
    unsafeAtomicAdd(o + 2, x[2] * v);
    unsafeAtomicAdd(o + 3, x[3] * v);
}

__global__ __launch_bounds__(256)
void gemm_relu_fb(const float* __restrict__ Xself, const float* __restrict__ Neigh,
                  const float* __restrict__ Wself, const float* __restrict__ Wneigh,
                  float* __restrict__ out, int nRows)
{
    const int tid  = threadIdx.x;
    const int wave = tid >> 6;
    const int lane = tid & 63;
    const int l15  = lane & 15;
    const int lhi  = lane >> 4;

    bf16x8 bfrag[2][8];
#pragma unroll
    for (int n = 0; n < 2; ++n) {
        int j = wave * 32 + n * 16 + l15;
#pragma unroll
        for (int kb = 0; kb < 8; ++kb) {
            int k = kb * 32 + lhi * 8;
            const float* src = (kb < 4) ? (Wself + j * D + k)
                                        : (Wneigh + j * D + (k - 128));
            f32x4 lo = *reinterpret_cast<const f32x4*>(src);
            f32x4 hi = *reinterpret_cast<const f32x4*>(src + 4);
            bfrag[n][kb] = pack8(lo, hi);
        }
    }

    int r0base = blockIdx.x * 128;
#pragma unroll 1
    for (int it = 0; it < 8; ++it) {
        int r0 = r0base + it * 16;
        if (r0 >= nRows) break;
        const float* xrow = Xself + (size_t)(r0 + l15) * D;
        const float* nrow = Neigh + (size_t)(r0 + l15) * D;
        bf16x8 afrag[8];
#pragma unroll
        for (int kb = 0; kb < 8; ++kb) {
            const float* src = (kb < 4) ? (xrow + kb * 32 + lhi * 8)
                                        : (nrow + (kb - 4) * 32 + lhi * 8);
            f32x4 lo = *reinterpret_cast<const f32x4*>(src);
            f32x4 hi = *reinterpret_cast<const f32x4*>(src + 4);
            afrag[kb] = pack8(lo, hi);
        }
        asm volatile("s_waitcnt vmcnt(0)" ::: "memory");
        __syncthreads();

        f32x4 acc0 = {0.f, 0.f, 0.f, 0.f};
        f32x4 acc1 = {0.f, 0.f, 0.f, 0.f};
#pragma unroll
        for (int kb = 0; kb < 8; ++kb) {
            acc0 = __builtin_amdgcn_mfma_f32_16x16x32_bf16(afrag[kb], bfrag[0][kb], acc0, 0, 0, 0);
            acc1 = __builtin_amdgcn_mfma_f32_16x16x32_bf16(afrag[kb], bfrag[1][kb], acc1, 0, 0, 0);
        }
#pragma unroll
        for (int i = 0; i < 4; ++i) {
            int rr = r0 + lhi * 4 + i;
            if (rr < nRows) {
                float v0 = acc0[i] > 0.f ? acc0[i] : 0.f;
                float v1 = acc1[i] > 0.f ? acc1[i] : 0.f;
                out[(size_t)rr * D + wave * 32 + l15]      = v0;
                out[(size_t)rr * D + wave * 32 + 16 + l15] = v1;
            }
        }
    }
}

// ---------------- launch ----------------

extern "C" void kernel_launch(void* const* d_in, const int* in_sizes, int n_in,
                              void* d_out, int out_size, void* d_ws, size_t ws_size,
                              hipStream_t stream)
{
    const float* Xg_self  = (const float*)d_in[0];
    const float* Xs_self  = (const float*)d_in[1];
    const float* Xs_for_g = (const float*)d_in[2];
    const float* Xg_for_s = (const float*)d_in[3];
    const int*   row_gs   = (const int*)d_in[4];
    const int*   col_gs   = (const int*)d_in[5];
    const float* val_gs   = (const float*)d_in[6];
    const int*   row_sg   = (const int*)d_in[7];
    const int*   col_sg   = (const int*)d_in[8];
    const float* val_sg   = (const float*)d_in[9];
    const float* Wg_self  = (const float*)d_in[10];
    const float* Wg_neigh = (const float*)d_in[11];
    const float* Ws_self  = (const float*)d_in[12];
    const float* Ws_neigh = (const float*)d_in[13];

    const int NG = in_sizes[0] / D;
    const int NS = in_sizes[1] / D;
    const int E1 = in_sizes[4];
    const int E2 = in_sizes[7];
    const int N  = NG + NS;
    const int Etot = E1 + E2;

    float* out_g = (float*)d_out;
    float* out_s = out_g + (size_t)NG * D;

    // ---- workspace layout ----
    size_t off = 0;
    auto alloc = [&](size_t bytes) -> size_t {
        off = (off + 255) & ~(size_t)255;
        size_t o = off;
        off += bytes;
        return o;
    };
    size_t x16g_o   = alloc(sizeof(short) * (size_t)NG * D);
    size_t x16s_o   = alloc(sizeof(short) * (size_t)NS * D);
    size_t wcat_o   = alloc(sizeof(short) * 2 * 128 * 256);
    size_t cnt_o    = alloc(sizeof(int) * N);
    size_t cursor_o = alloc(sizeof(int) * N);
    size_t pairs_o  = alloc(sizeof(int2) * (size_t)Etot);
    size_t blk_o    = alloc(sizeof(int) * 1024);
    size_t neigh_o  = alloc(sizeof(short) * (size_t)N * D);
    size_t need_bytes = off;

    char* ws = (char*)d_ws;

    if (ws_size < need_bytes) {
        // ---- deep fallback: atomic scatter + in-place register GEMM ----
        hipMemsetAsync(d_out, 0, (size_t)out_size * sizeof(float), stream);
        {
            long long threads = (long long)E1 * 32;
            scatter_edges<<<(int)((threads + 255) / 256), 256, 0, stream>>>(
                Xs_for_g, row_gs, col_gs, val_gs, out_g, E1);
        }
        {
            long long threads = (long long)E2 * 32;
            scatter_edges<<<(int)((threads + 255) / 256), 256, 0, stream>>>(
                Xg_for_s, row_sg, col_sg, val_sg, out_s, E2);
        }
        gemm_relu_fb<<<(NG + 127) / 128, 256, 0, stream>>>(Xg_self, out_g, Wg_self, Wg_neigh, out_g, NG);
        gemm_relu_fb<<<(NS + 127) / 128, 256, 0, stream>>>(Xs_self, out_s, Ws_self, Ws_neigh, out_s, NS);
        return;
    }

    unsigned short* x16g    = (unsigned short*)(ws + x16g_o);
    unsigned short* x16s    = (unsigned short*)(ws + x16s_o);
    short* wcat             = (short*)(ws + wcat_o);
    int* cnt                = (int*)(ws + cnt_o);
    int* cursor             = (int*)(ws + cursor_o);
    int2* pairs             = (int2*)(ws + pairs_o);
    int* blk                = (int*)(ws + blk_o);
    unsigned short* neigh16 = (unsigned short*)(ws + neigh_o);

    const int n8a = NG * D / 8, n8b = NS * D / 8;

    hipMemsetAsync(cnt, 0, sizeof(int) * N, stream);

    {
        long long tot = (long long)n8a + n8b + 2 * 128 * 32 + Etot;
        prep_kernel<<<(int)((tot + 255) / 256), 256, 0, stream>>>(
            Xs_for_g, Xg_for_s, x16g, x16s,
            Wg_self, Wg_neigh, Ws_self, Ws_neigh, wcat,
            row_gs, E1, row_sg, NG, cnt, n8a, n8b, Etot);
    }

    int nb = (N + 1023) / 1024;   // 196 <= 256
    scan1_kernel<<<nb, 256, 0, stream>>>(cnt, cursor, blk, N);
    scan2_kernel<<<1, 256, 0, stream>>>(blk, nb);
    scan3_kernel<<<(N + 255) / 256, 256, 0, stream>>>(cursor, blk, N);

    {
        int nchunks = (Etot + FILL_CHUNK - 1) / FILL_CHUNK;
        fill2x_kernel<<<nchunks * 8, 256, 0, stream>>>(
            row_gs, col_gs, val_gs, E1, row_sg, col_sg, val_sg, NG, cursor, pairs, Etot);
    }

    gather_kernel<<<(int)(((long long)N * 64 + 255) / 256), 256, 0, stream>>>(
        x16g, x16s, cnt, cursor, pairs, neigh16, NG, N);

    int blocks0 = (NG + 31) / 32, blocks1 = (NS + 31) / 32;
    gemm16c_kernel<<<blocks0 + blocks1, 256, 0, stream>>>(
        Xg_self, Xs_self, neigh16, out_g, NG, out_s, NS, wcat);
}

// Round 14
// 297.710 us; speedup vs baseline: 1.1117x; 1.1090x over previous
//
#include <hip/hip_runtime.h>
#include <hip/hip_bf16.h>
#include <stdint.h>

typedef __attribute__((ext_vector_type(4))) float f32x4;
typedef __attribute__((ext_vector_type(8))) short bf16x8;

#define D 128
#define GLOBAL_AS __attribute__((address_space(1)))
#define LDS_AS __attribute__((address_space(3)))

__device__ inline short f2bf(float x) {
    __hip_bfloat16 h = __float2bfloat16(x);
    return __builtin_bit_cast(short, h);
}

__device__ inline bf16x8 pack8(f32x4 lo, f32x4 hi) {
    bf16x8 b;
    b[0] = f2bf(lo[0]); b[1] = f2bf(lo[1]); b[2] = f2bf(lo[2]); b[3] = f2bf(lo[3]);
    b[4] = f2bf(hi[0]); b[5] = f2bf(hi[1]); b[6] = f2bf(hi[2]); b[7] = f2bf(hi[3]);
    return b;
}

__device__ inline unsigned int pack2bf(float a, float b) {
    unsigned int ua = (unsigned int)(unsigned short)f2bf(a);
    unsigned int ub = (unsigned int)(unsigned short)f2bf(b);
    return ua | (ub << 16);
}

// ---- prep2: pack weights + row histogram only (X conversions moved to fillconv) ----

__global__ __launch_bounds__(256)
void prep2_kernel(const float* __restrict__ Wg_self, const float* __restrict__ Wg_neigh,
                  const float* __restrict__ Ws_self, const float* __restrict__ Ws_neigh,
                  short* __restrict__ Wcat,
                  const int* __restrict__ rowA, int EA,
                  const int* __restrict__ rowB, int NGoff,
                  int* __restrict__ cnt, int Etot)
{
    int t = blockIdx.x * 256 + threadIdx.x;
    if (t < 2 * 128 * 32) {
        int dir = t >> 12;
        int rem = t & 4095;
        int j = rem >> 5;
        int k = (rem & 31) * 8;
        const float* Wself  = dir ? Ws_self  : Wg_self;
        const float* Wneigh = dir ? Ws_neigh : Wg_neigh;
        const float* src = (k < 128) ? (Wself + j * D + k) : (Wneigh + j * D + (k - 128));
        f32x4 lo = *reinterpret_cast<const f32x4*>(src);
        f32x4 hi = *reinterpret_cast<const f32x4*>(src + 4);
        *reinterpret_cast<bf16x8*>(Wcat + (size_t)dir * 32768 + j * 256 + k) = pack8(lo, hi);
        return;
    }
    t -= 2 * 128 * 32;
    if (t < Etot) {
        int r = (t < EA) ? rowA[t] : (rowB[t - EA] + NGoff);
        atomicAdd(&cnt[r], 1);
    }
}

// ---------------- scans ----------------

__global__ __launch_bounds__(256)
void scan1_kernel(const int* __restrict__ cnt, int* __restrict__ part,
                  int* __restrict__ blksums, int N)
{
    __shared__ int wsum[4];
    int t = threadIdx.x;
    int base = blockIdx.x * 1024 + t * 4;
    int v0 = base + 0 < N ? cnt[base + 0] : 0;
    int v1 = base + 1 < N ? cnt[base + 1] : 0;
    int v2 = base + 2 < N ? cnt[base + 2] : 0;
    int v3 = base + 3 < N ? cnt[base + 3] : 0;
    int s = v0 + v1 + v2 + v3;
    int lane = t & 63, w = t >> 6;
    int x = s;
#pragma unroll
    for (int off = 1; off < 64; off <<= 1) {
        int y = __shfl_up(x, off);
        if (lane >= off) x += y;
    }
    if (lane == 63) wsum[w] = x;
    __syncthreads();
    int woff = 0;
    for (int i = 0; i < w; ++i) woff += wsum[i];
    int incl = x + woff;
    int excl = incl - s;
    if (base + 0 < N) part[base + 0] = excl;
    if (base + 1 < N) part[base + 1] = excl + v0;
    if (base + 2 < N) part[base + 2] = excl + v0 + v1;
    if (base + 3 < N) part[base + 3] = excl + v0 + v1 + v2;
    if (t == 255) blksums[blockIdx.x] = incl;
}

__global__ __launch_bounds__(256)
void scan2_kernel(int* __restrict__ blksums, int nb)
{
    __shared__ int wsum[4];
    int t = threadIdx.x;
    int v = t < nb ? blksums[t] : 0;
    int lane = t & 63, w = t >> 6;
    int x = v;
#pragma unroll
    for (int off = 1; off < 64; off <<= 1) {
        int y = __shfl_up(x, off);
        if (lane >= off) x += y;
    }
    if (lane == 63) wsum[w] = x;
    __syncthreads();
    int woff = 0;
    for (int i = 0; i < w; ++i) woff += wsum[i];
    int excl = x + woff - v;
    if (t < nb) blksums[t] = excl;
}

__global__ __launch_bounds__(256)
void scan3_kernel(int* __restrict__ cursor, const int* __restrict__ blksums, int N)
{
    int i = blockIdx.x * 256 + threadIdx.x;
    if (i < N) cursor[i] += blksums[i >> 10];
}

// ---- fused fill + X-table conversion ----
// Blocks [0, nFill): XCD-partitioned CSR fill (proven R11): 8 blocks per chunk,
// block grp only scatters edges with ((gid>>6)&7)==grp -> each XCD L2 dirties
// 1/8 of pairs (write amp ~1). Latency-bound, low BW.
// Blocks [nFill, ...): streaming f32->bf16 conversion of both X tables (BW-bound).
// Fusing them in one launch lets the two regimes co-schedule on the CUs.
#define FILL_CHUNK 2048
__global__ __launch_bounds__(256)
void fillconv_kernel(const int* __restrict__ rowA, const int* __restrict__ colA,
                     const float* __restrict__ valA, int EA,
                     const int* __restrict__ rowB, const int* __restrict__ colB,
                     const float* __restrict__ valB, int NGoff,
                     int* __restrict__ cursor, int2* __restrict__ pairs, int Etot,
                     int nFill,
                     const float* __restrict__ Xa, const float* __restrict__ Xb,
                     unsigned short* __restrict__ x16a, unsigned short* __restrict__ x16b,
                     int n8a, int n8b)
{
    if ((int)blockIdx.x < nFill) {
        int chunk = blockIdx.x >> 3;
        int grp   = blockIdx.x & 7;
        int base  = chunk * FILL_CHUNK;
#pragma unroll 1
        for (int i = threadIdx.x; i < FILL_CHUNK; i += 256) {
            int e = base + i;
            if (e >= Etot) break;
            int gid = (e < EA) ? rowA[e] : (rowB[e - EA] + NGoff);
            if (((gid >> 6) & 7) != grp) continue;
            int c; float v;
            if (e < EA) { c = colA[e]; v = valA[e]; }
            else { int e2 = e - EA; c = colB[e2]; v = valB[e2]; }
            int p = atomicAdd(&cursor[gid], 1);
            pairs[p] = make_int2(c, __float_as_int(v));
        }
        return;
    }
    int t = ((int)blockIdx.x - nFill) * 256 + threadIdx.x;
    if (t < n8a) {
        f32x4 lo = *reinterpret_cast<const f32x4*>(Xa + (size_t)t * 8);
        f32x4 hi = *reinterpret_cast<const f32x4*>(Xa + (size_t)t * 8 + 4);
        *reinterpret_cast<bf16x8*>(x16a + (size_t)t * 8) = pack8(lo, hi);
        return;
    }
    t -= n8a;
    if (t < n8b) {
        f32x4 lo = *reinterpret_cast<const f32x4*>(Xb + (size_t)t * 8);
        f32x4 hi = *reinterpret_cast<const f32x4*>(Xb + (size_t)t * 8 + 4);
        *reinterpret_cast<bf16x8*>(x16b + (size_t)t * 8) = pack8(lo, hi);
    }
}

// ---------------- standalone gather: one WAVE per row, bf16 table -> bf16 neigh ----
__global__ __launch_bounds__(256)
void gather_kernel(const unsigned short* __restrict__ X16_0,
                   const unsigned short* __restrict__ X16_1,
                   const int* __restrict__ cnt, const int* __restrict__ endpos,
                   const int2* __restrict__ pairs,
                   unsigned short* __restrict__ neigh16, int NG, int N)
{
    int wid = (blockIdx.x * 256 + threadIdx.x) >> 6;
    if (wid >= N) return;
    int lane = threadIdx.x & 63;
    const unsigned short* X16 = (wid < NG) ? X16_0 : X16_1;
    int n = __builtin_amdgcn_readfirstlane(cnt[wid]);
    int s = __builtin_amdgcn_readfirstlane(endpos[wid]) - n;
    float acc0 = 0.f, acc1 = 0.f;
#pragma unroll 1
    for (int j = 0; j < n; j += 8) {
        int2 p[8]; unsigned int x[8];
#pragma unroll
        for (int u = 0; u < 8; ++u) {
            int idx = (j + u < n) ? j + u : n - 1;
            p[u] = pairs[s + idx];
        }
#pragma unroll
        for (int u = 0; u < 8; ++u)
            x[u] = *reinterpret_cast<const unsigned int*>(X16 + (size_t)p[u].x * D + lane * 2);
#pragma unroll
        for (int u = 0; u < 8; ++u) {
            float v = (j + u < n) ? __int_as_float(p[u].y) : 0.f;
            acc0 += __uint_as_float(x[u] << 16) * v;
            acc1 += __uint_as_float(x[u] & 0xffff0000u) * v;
        }
    }
    ((unsigned int*)neigh16)[(size_t)wid * 64 + lane] = pack2bf(acc0, acc1);
}

// ---------------- GEMM + relu (R11 proven version) ----------------
__global__ __launch_bounds__(256)
void gemm16_kernel(const float* __restrict__ Xself0, const float* __restrict__ Xself1,
                   const unsigned short* __restrict__ neigh16,
                   float* __restrict__ out0, int n0,
                   float* __restrict__ out1, int n1,
                   const short* __restrict__ Wcat)
{
    __shared__ float A[32 * 128];   // 16 KiB: 32 Xself rows (512B each)
    const int ROWS = 32;
    int blocks0 = (n0 + ROWS - 1) / ROWS;

    const float* Xself; float* out; int nRows, r0base, csr0; const short* Wb;
    if ((int)blockIdx.x < blocks0) {
        Xself = Xself0; out = out0; nRows = n0;
        r0base = blockIdx.x * ROWS; csr0 = 0; Wb = Wcat;
    } else {
        Xself = Xself1; out = out1; nRows = n1;
        r0base = ((int)blockIdx.x - blocks0) * ROWS; csr0 = n0; Wb = Wcat + 32768;
    }

    const int tid = threadIdx.x, wave = tid >> 6, lane = tid & 63;
    const int l15 = lane & 15, lhi = lane >> 4;

    // ---- stage 8 Xself rows per wave (2 rows per instruction) ----
#pragma unroll
    for (int i = 0; i < 8; i += 2) {
        int r = wave * 8 + i + (lane >> 5);
        int R = r0base + r; if (R > nRows - 1) R = nRows - 1;
        const float* g = Xself + (size_t)R * D + (((lane & 31) ^ (r & 7)) << 2);
        __builtin_amdgcn_global_load_lds((const GLOBAL_AS uint32_t*)g,
                                         (LDS_AS uint32_t*)(&A[(wave * 8 + i) * 128]),
                                         16, 0, 0);
    }

    // ---- weight fragments ----
    bf16x8 bfrag[2][8];
#pragma unroll
    for (int nn = 0; nn < 2; ++nn) {
        int j = wave * 32 + nn * 16 + l15;
#pragma unroll
        for (int kb = 0; kb < 8; ++kb)
            bfrag[nn][kb] = *reinterpret_cast<const bf16x8*>(
                Wb + (size_t)j * 256 + kb * 32 + lhi * 8);
    }

    // ---- neigh fragments direct from global (bf16, no pack needed) ----
    bf16x8 nfrag[2][4];
#pragma unroll
    for (int it = 0; it < 2; ++it) {
        int R = r0base + it * 16 + l15; if (R > nRows - 1) R = nRows - 1;
#pragma unroll
        for (int k4 = 0; k4 < 4; ++k4)
            nfrag[it][k4] = *reinterpret_cast<const bf16x8*>(
                neigh16 + (size_t)(csr0 + R) * D + k4 * 32 + lhi * 8);
    }

    asm volatile("s_waitcnt vmcnt(0)" ::: "memory");
    __syncthreads();

    // ---- MFMA + relu + store ----
#pragma unroll
    for (int it = 0; it < 2; ++it) {
        int r = it * 16 + l15;
        int rx = r & 7;
        f32x4 acc0 = {0.f, 0.f, 0.f, 0.f};
        f32x4 acc1 = {0.f, 0.f, 0.f, 0.f};
#pragma unroll
        for (int kb = 0; kb < 8; ++kb) {
            bf16x8 af;
            if (kb < 4) {
                int c0 = kb * 8 + lhi * 2;   // 16B chunk 0..31 within the 512B row
                f32x4 lo = *reinterpret_cast<const f32x4*>(&A[r * 128 + ((c0 ^ rx) << 2)]);
                f32x4 hi = *reinterpret_cast<const f32x4*>(&A[r * 128 + (((c0 + 1) ^ rx) << 2)]);
                af = pack8(lo, hi);
            } else {
                af = nfrag[it][kb - 4];
            }
            acc0 = __builtin_amdgcn_mfma_f32_16x16x32_bf16(af, bfrag[0][kb], acc0, 0, 0, 0);
            acc1 = __builtin_amdgcn_mfma_f32_16x16x32_bf16(af, bfrag[1][kb], acc1, 0, 0, 0);
        }
        // C/D layout: col = lane&15, row = (lane>>4)*4 + reg.
#pragma unroll
        for (int i2 = 0; i2 < 4; ++i2) {
            int rr = r0base + it * 16 + lhi * 4 + i2;
            if (rr < nRows) {
                float v0 = acc0[i2] > 0.f ? acc0[i2] : 0.f;
                float v1 = acc1[i2] > 0.f ? acc1[i2] : 0.f;
                out[(size_t)rr * D + wave * 32 + l15]      = v0;
                out[(size_t)rr * D + wave * 32 + 16 + l15] = v1;
            }
        }
    }
}

// ---------------- deep fallback: atomic scatter + register GEMM ------

__global__ __launch_bounds__(256)
void scatter_edges(const float* __restrict__ X, const int* __restrict__ row,
                   const int* __restrict__ col, const float* __restrict__ val,
                   float* out, int nE)
{
    int t = blockIdx.x * 256 + threadIdx.x;
    int e = t >> 5;
    if (e >= nE) return;
    int l = t & 31;
    int r = row[e];
    int c = col[e];
    float v = val[e];
    f32x4 x = *reinterpret_cast<const f32x4*>(X + (size_t)c * D + l * 4);
    float* o = out + (size_t)r * D + l * 4;
    unsafeAtomicAdd(o + 0, x[0] * v);
    unsafeAtomicAdd(o + 1, x[1] * v);
    unsafeAtomicAdd(o + 2, x[2] * v);
    unsafeAtomicAdd(o + 3, x[3] * v);
}

__global__ __launch_bounds__(256)
void gemm_relu_fb(const float* __restrict__ Xself, const float* __restrict__ Neigh,
                  const float* __restrict__ Wself, const float* __restrict__ Wneigh,
                  float* __restrict__ out, int nRows)
{
    const int tid  = threadIdx.x;
    const int wave = tid >> 6;
    const int lane = tid & 63;
    const int l15  = lane & 15;
    const int lhi  = lane >> 4;

    bf16x8 bfrag[2][8];
#pragma unroll
    for (int n = 0; n < 2; ++n) {
        int j = wave * 32 + n * 16 + l15;
#pragma unroll
        for (int kb = 0; kb < 8; ++kb) {
            int k = kb * 32 + lhi * 8;
            const float* src = (kb < 4) ? (Wself + j * D + k)
                                        : (Wneigh + j * D + (k - 128));
            f32x4 lo = *reinterpret_cast<const f32x4*>(src);
            f32x4 hi = *reinterpret_cast<const f32x4*>(src + 4);
            bfrag[n][kb] = pack8(lo, hi);
        }
    }

    int r0base = blockIdx.x * 128;
#pragma unroll 1
    for (int it = 0; it < 8; ++it) {
        int r0 = r0base + it * 16;
        if (r0 >= nRows) break;
        const float* xrow = Xself + (size_t)(r0 + l15) * D;
        const float* nrow = Neigh + (size_t)(r0 + l15) * D;
        bf16x8 afrag[8];
#pragma unroll
        for (int kb = 0; kb < 8; ++kb) {
            const float* src = (kb < 4) ? (xrow + kb * 32 + lhi * 8)
                                        : (nrow + (kb - 4) * 32 + lhi * 8);
            f32x4 lo = *reinterpret_cast<const f32x4*>(src);
            f32x4 hi = *reinterpret_cast<const f32x4*>(src + 4);
            afrag[kb] = pack8(lo, hi);
        }
        asm volatile("s_waitcnt vmcnt(0)" ::: "memory");
        __syncthreads();

        f32x4 acc0 = {0.f, 0.f, 0.f, 0.f};
        f32x4 acc1 = {0.f, 0.f, 0.f, 0.f};
#pragma unroll
        for (int kb = 0; kb < 8; ++kb) {
            acc0 = __builtin_amdgcn_mfma_f32_16x16x32_bf16(afrag[kb], bfrag[0][kb], acc0, 0, 0, 0);
            acc1 = __builtin_amdgcn_mfma_f32_16x16x32_bf16(afrag[kb], bfrag[1][kb], acc1, 0, 0, 0);
        }
#pragma unroll
        for (int i = 0; i < 4; ++i) {
            int rr = r0 + lhi * 4 + i;
            if (rr < nRows) {
                float v0 = acc0[i] > 0.f ? acc0[i] : 0.f;
                float v1 = acc1[i] > 0.f ? acc1[i] : 0.f;
                out[(size_t)rr * D + wave * 32 + l15]      = v0;
                out[(size_t)rr * D + wave * 32 + 16 + l15] = v1;
            }
        }
    }
}

// ---------------- launch ----------------

extern "C" void kernel_launch(void* const* d_in, const int* in_sizes, int n_in,
                              void* d_out, int out_size, void* d_ws, size_t ws_size,
                              hipStream_t stream)
{
    const float* Xg_self  = (const float*)d_in[0];
    const float* Xs_self  = (const float*)d_in[1];
    const float* Xs_for_g = (const float*)d_in[2];
    const float* Xg_for_s = (const float*)d_in[3];
    const int*   row_gs   = (const int*)d_in[4];
    const int*   col_gs   = (const int*)d_in[5];
    const float* val_gs   = (const float*)d_in[6];
    const int*   row_sg   = (const int*)d_in[7];
    const int*   col_sg   = (const int*)d_in[8];
    const float* val_sg   = (const float*)d_in[9];
    const float* Wg_self  = (const float*)d_in[10];
    const float* Wg_neigh = (const float*)d_in[11];
    const float* Ws_self  = (const float*)d_in[12];
    const float* Ws_neigh = (const float*)d_in[13];

    const int NG = in_sizes[0] / D;
    const int NS = in_sizes[1] / D;
    const int E1 = in_sizes[4];
    const int E2 = in_sizes[7];
    const int N  = NG + NS;
    const int Etot = E1 + E2;

    float* out_g = (float*)d_out;
    float* out_s = out_g + (size_t)NG * D;

    // ---- workspace layout ----
    size_t off = 0;
    auto alloc = [&](size_t bytes) -> size_t {
        off = (off + 255) & ~(size_t)255;
        size_t o = off;
        off += bytes;
        return o;
    };
    size_t x16g_o   = alloc(sizeof(short) * (size_t)NG * D);
    size_t x16s_o   = alloc(sizeof(short) * (size_t)NS * D);
    size_t wcat_o   = alloc(sizeof(short) * 2 * 128 * 256);
    size_t cnt_o    = alloc(sizeof(int) * N);
    size_t cursor_o = alloc(sizeof(int) * N);
    size_t pairs_o  = alloc(sizeof(int2) * (size_t)Etot);
    size_t blk_o    = alloc(sizeof(int) * 1024);
    size_t neigh_o  = alloc(sizeof(short) * (size_t)N * D);
    size_t need_bytes = off;

    char* ws = (char*)d_ws;

    if (ws_size < need_bytes) {
        // ---- deep fallback: atomic scatter + in-place register GEMM ----
        hipMemsetAsync(d_out, 0, (size_t)out_size * sizeof(float), stream);
        {
            long long threads = (long long)E1 * 32;
            scatter_edges<<<(int)((threads + 255) / 256), 256, 0, stream>>>(
                Xs_for_g, row_gs, col_gs, val_gs, out_g, E1);
        }
        {
            long long threads = (long long)E2 * 32;
            scatter_edges<<<(int)((threads + 255) / 256), 256, 0, stream>>>(
                Xg_for_s, row_sg, col_sg, val_sg, out_s, E2);
        }
        gemm_relu_fb<<<(NG + 127) / 128, 256, 0, stream>>>(Xg_self, out_g, Wg_self, Wg_neigh, out_g, NG);
        gemm_relu_fb<<<(NS + 127) / 128, 256, 0, stream>>>(Xs_self, out_s, Ws_self, Ws_neigh, out_s, NS);
        return;
    }

    unsigned short* x16g    = (unsigned short*)(ws + x16g_o);
    unsigned short* x16s    = (unsigned short*)(ws + x16s_o);
    short* wcat             = (short*)(ws + wcat_o);
    int* cnt                = (int*)(ws + cnt_o);
    int* cursor             = (int*)(ws + cursor_o);
    int2* pairs             = (int2*)(ws + pairs_o);
    int* blk                = (int*)(ws + blk_o);
    unsigned short* neigh16 = (unsigned short*)(ws + neigh_o);

    const int n8a = NG * D / 8, n8b = NS * D / 8;

    hipMemsetAsync(cnt, 0, sizeof(int) * N, stream);

    {
        long long tot = (long long)2 * 128 * 32 + Etot;
        prep2_kernel<<<(int)((tot + 255) / 256), 256, 0, stream>>>(
            Wg_self, Wg_neigh, Ws_self, Ws_neigh, wcat,
            row_gs, E1, row_sg, NG, cnt, Etot);
    }

    int nb = (N + 1023) / 1024;   // 196 <= 256
    scan1_kernel<<<nb, 256, 0, stream>>>(cnt, cursor, blk, N);
    scan2_kernel<<<1, 256, 0, stream>>>(blk, nb);
    scan3_kernel<<<(N + 255) / 256, 256, 0, stream>>>(cursor, blk, N);

    {
        int nFill = ((Etot + FILL_CHUNK - 1) / FILL_CHUNK) * 8;
        int nConv = (n8a + n8b + 255) / 256;
        fillconv_kernel<<<nFill + nConv, 256, 0, stream>>>(
            row_gs, col_gs, val_gs, E1, row_sg, col_sg, val_sg, NG,
            cursor, pairs, Etot, nFill,
            Xs_for_g, Xg_for_s, x16g, x16s, n8a, n8b);
    }

    gather_kernel<<<(int)(((long long)N * 64 + 255) / 256), 256, 0, stream>>>(
        x16g, x16s, cnt, cursor, pairs, neigh16, NG, N);

    int blocks0 = (NG + 31) / 32, blocks1 = (NS + 31) / 32;
    gemm16_kernel<<<blocks0 + blocks1, 256, 0, stream>>>(
        Xg_self, Xs_self, neigh16, out_g, NG, out_s, NS, wcat);
}